// Round 1
// baseline (301.370 us; speedup 1.0000x reference)
//
#include <hip/hip_runtime.h>

// Sparse 3D neighborhood attention (causal), MI355X fp32 baseline.
// Shapes: x (4609, 512); video 8x24x24 = 4608 tokens + 1 BOS.
// HEADS=8, DHEAD=64. Neighbors: BOS + 27 (3x3x3 causal window, left-pad only).

constexpr int TFR   = 8;
constexpr int SDIM  = 24;
constexpr int NVID  = TFR * SDIM * SDIM;   // 4608
constexpr int NTOK  = NVID + 1;            // 4609
constexpr int NH    = 8;
constexpr int DH    = 64;
constexpr int DM    = 512;                 // model dim
constexpr int NJ    = 28;                  // BOS + 27 neighbors

// ---------------------------------------------------------------------------
// Tiled fp32 GEMM: C = A(MxK) @ B(KxN) (+ bias). BM=BN=64, BK=16, 256 thr,
// 4x4 microtile per thread. A staged transposed (Ast[k][m], pad 4) so both
// operand reads are ds_read_b128.
// ---------------------------------------------------------------------------
__global__ __launch_bounds__(256)
void gemm_f32(const float* __restrict__ A, const float* __restrict__ B,
              float* __restrict__ C, int M, int N, int K,
              const float* __restrict__ bias)
{
    constexpr int BM = 64, BN = 64, BK = 16;
    __shared__ float Ast[BK][BM + 4];   // [k][m], +4 keeps 16B alignment
    __shared__ float Bs[BK][BN];        // [k][n]

    const int tid = threadIdx.x;
    const int tx  = tid & 15;           // n-direction
    const int ty  = tid >> 4;           // m-direction
    const int m0  = blockIdx.x * BM;
    const int n0  = blockIdx.y * BN;

    // A staging: thread loads A[m0 + tid/4][k0 + (tid%4)*4 .. +3]
    const int a_row = tid >> 2;          // 0..63
    const int a_col = (tid & 3) * 4;     // 0,4,8,12
    // B staging: thread loads B[k0 + tid/16][n0 + (tid%16)*4 .. +3]
    const int b_row = tid >> 4;          // 0..15
    const int b_col = (tid & 15) * 4;

    float acc[4][4] = {};

    for (int k0 = 0; k0 < K; k0 += BK) {
        float4 av = make_float4(0.f, 0.f, 0.f, 0.f);
        const int gm = m0 + a_row;
        if (gm < M)
            av = *(const float4*)(A + (size_t)gm * K + k0 + a_col);
        Ast[a_col + 0][a_row] = av.x;
        Ast[a_col + 1][a_row] = av.y;
        Ast[a_col + 2][a_row] = av.z;
        Ast[a_col + 3][a_row] = av.w;

        const float4 bv = *(const float4*)(B + (size_t)(k0 + b_row) * N + n0 + b_col);
        *(float4*)(&Bs[b_row][b_col]) = bv;
        __syncthreads();

        #pragma unroll
        for (int kk = 0; kk < BK; ++kk) {
            float4 a4 = *(const float4*)(&Ast[kk][ty * 4]);
            float4 b4 = *(const float4*)(&Bs[kk][tx * 4]);
            float a[4] = {a4.x, a4.y, a4.z, a4.w};
            float b[4] = {b4.x, b4.y, b4.z, b4.w};
            #pragma unroll
            for (int r = 0; r < 4; ++r)
                #pragma unroll
                for (int c = 0; c < 4; ++c)
                    acc[r][c] += a[r] * b[c];
        }
        __syncthreads();
    }

    #pragma unroll
    for (int r = 0; r < 4; ++r) {
        const int gm = m0 + ty * 4 + r;
        if (gm >= M) continue;
        const int gn = n0 + tx * 4;
        float4 o = make_float4(acc[r][0], acc[r][1], acc[r][2], acc[r][3]);
        if (bias) {
            o.x += bias[gn + 0]; o.y += bias[gn + 1];
            o.z += bias[gn + 2]; o.w += bias[gn + 3];
        }
        *(float4*)(C + (size_t)gm * N + gn) = o;
    }
}

// ---------------------------------------------------------------------------
// Fused attention: one block (256 thr) per video query position.
// All 8 heads handled in-block so talking-heads mixing is local.
// KV layout: row r (0..4608) = [K(512) | V(512)], column = h*64+d.
// ---------------------------------------------------------------------------
__global__ __launch_bounds__(256)
void attn_kernel(const float* __restrict__ Q, const float* __restrict__ KV,
                 float* __restrict__ O,
                 const float* __restrict__ W_th,
                 const float* __restrict__ ax1, const float* __restrict__ ax2,
                 const float* __restrict__ ax3)
{
    __shared__ float q_s[DM];
    __shared__ float sim_s[NH * NJ];     // becomes attn after softmax
    __shared__ float mixed_s[NH * NJ];
    __shared__ float bias_s[NH * NJ];
    __shared__ int   row_s[NJ];

    const int tid  = threadIdx.x;
    const int i    = blockIdx.x;         // video position 0..4607
    const int qrow = i + 1;

    // stage scaled q (scale = 1/sqrt(64) = 0.125)
    q_s[tid]       = Q[(size_t)qrow * DM + tid]       * 0.125f;
    q_s[tid + 256] = Q[(size_t)qrow * DM + tid + 256] * 0.125f;

    if (tid < NJ) {
        int row;
        if (tid == 0) {
            row = 0;                     // BOS
        } else {
            const int jp = tid - 1;
            const int di = jp / 9, dj = (jp / 3) % 3, dk = jp % 3;
            const int t  = i / (SDIM * SDIM);
            const int rm = i % (SDIM * SDIM);
            const int y  = rm / SDIM, x = rm % SDIM;
            const int tt = t + di - 2, yy = y + dj - 2, xx = x + dk - 2;
            row = (tt >= 0 && yy >= 0 && xx >= 0)
                    ? (1 + tt * SDIM * SDIM + yy * SDIM + xx) : -1;
        }
        row_s[tid] = row;
    }
    if (tid < NH * NJ) {
        const int g = tid / NJ, j = tid % NJ;
        float b = 0.f;
        if (j > 0) {
            const int jp = j - 1;
            const int di = jp / 9, dj = (jp / 3) % 3, dk = jp % 3;
            b = ax1[di * NH + g] + ax2[dj * NH + g] + ax3[dk * NH + g];
        }
        bias_s[tid] = b;
    }
    __syncthreads();

    // sim[g][j] = q[g] . k_neighbor[j][g] : 224 dots of length 64.
    // 16 lanes per dot (float4 each), shuffle-reduce within 16-lane group.
    const int wave = tid >> 6;
    const int lane = tid & 63;
    const int sub  = lane >> 4;          // 0..3
    const int ln   = lane & 15;          // 0..15
    #pragma unroll 2
    for (int step = 0; step < 14; ++step) {
        const int p   = step * 16 + wave * 4 + sub;  // 0..223, bijective
        const int g   = p / NJ, j = p % NJ;
        const int row = row_s[j];
        float partial = 0.f;
        if (row >= 0) {
            const float4 k4 = *(const float4*)(KV + (size_t)row * 1024 + g * 64 + ln * 4);
            const float4 q4 = *(const float4*)(&q_s[g * 64 + ln * 4]);
            partial = k4.x * q4.x + k4.y * q4.y + k4.z * q4.z + k4.w * q4.w;
        }
        partial += __shfl_xor(partial, 1);
        partial += __shfl_xor(partial, 2);
        partial += __shfl_xor(partial, 4);
        partial += __shfl_xor(partial, 8);
        if (ln == 0)
            sim_s[p] = (row >= 0) ? (partial + bias_s[p]) : -1e30f;
    }
    __syncthreads();

    // softmax per head (8 threads, serial over 28 — cheap)
    if (tid < NH) {
        float m = -1e30f;
        #pragma unroll
        for (int j = 0; j < NJ; ++j) m = fmaxf(m, sim_s[tid * NJ + j]);
        float e[NJ], s = 0.f;
        #pragma unroll
        for (int j = 0; j < NJ; ++j) {
            e[j] = __expf(sim_s[tid * NJ + j] - m);
            s += e[j];
        }
        const float inv = 1.f / s;
        #pragma unroll
        for (int j = 0; j < NJ; ++j) sim_s[tid * NJ + j] = e[j] * inv;
    }
    __syncthreads();

    // talking-heads: mixed[h][j] = sum_g W_th[h][g] * attn[g][j]
    if (tid < NH * NJ) {
        const int h = tid / NJ, j = tid % NJ;
        float acc = 0.f;
        #pragma unroll
        for (int g = 0; g < NH; ++g)
            acc += W_th[h * NH + g] * sim_s[g * NJ + j];
        mixed_s[tid] = acc;
    }
    __syncthreads();

    // out[h, i, d] = sum_j mixed[h][j] * V[row_j][h*64+d]; coalesced V reads.
    #pragma unroll
    for (int half = 0; half < 2; ++half) {
        const int c = tid + half * 256;       // = h*64+d
        const int h = c >> 6;
        float acc = 0.f;
        for (int j = 0; j < NJ; ++j) {
            const int row = row_s[j];
            if (row >= 0)
                acc += mixed_s[h * NJ + j] * KV[(size_t)row * 1024 + 512 + c];
        }
        O[(size_t)qrow * DM + c] = acc;
    }

    // BOS output row = v_bos (V row 0)
    if (i == 0) {
        O[tid]       = KV[512 + tid];
        O[tid + 256] = KV[512 + tid + 256];
    }
}

// ---------------------------------------------------------------------------
extern "C" void kernel_launch(void* const* d_in, const int* in_sizes, int n_in,
                              void* d_out, int out_size, void* d_ws, size_t ws_size,
                              hipStream_t stream)
{
    const float* x    = (const float*)d_in[0];
    const float* Wq   = (const float*)d_in[1];
    const float* Wkv  = (const float*)d_in[2];
    const float* W_th = (const float*)d_in[3];
    const float* Wout = (const float*)d_in[4];
    const float* bout = (const float*)d_in[5];
    const float* ax1  = (const float*)d_in[6];
    const float* ax2  = (const float*)d_in[7];
    const float* ax3  = (const float*)d_in[8];
    float* out = (float*)d_out;

    // workspace: Q (4609*512) | KV (4609*1024) | O (4609*512)  ~38 MB fp32
    float* Q  = (float*)d_ws;
    float* KV = Q  + (size_t)NTOK * DM;
    float* O  = KV + (size_t)NTOK * 1024;

    const dim3 blk(256);
    const int mtiles = (NTOK + 63) / 64;   // 73

    gemm_f32<<<dim3(mtiles, DM / 64),   blk, 0, stream>>>(x, Wq,  Q,  NTOK,  DM,  DM, nullptr);
    gemm_f32<<<dim3(mtiles, 1024 / 64), blk, 0, stream>>>(x, Wkv, KV, NTOK, 1024, DM, nullptr);
    attn_kernel<<<dim3(NVID), blk, 0, stream>>>(Q, KV, O, W_th, ax1, ax2, ax3);
    gemm_f32<<<dim3(mtiles, DM / 64),   blk, 0, stream>>>(O, Wout, out, NTOK, DM, DM, bout);
}

// Round 2
// 220.837 us; speedup vs baseline: 1.3647x; 1.3647x over previous
//
#include <hip/hip_runtime.h>
#include <hip/hip_bf16.h>

// Sparse 3D neighborhood attention (causal), MI355X. Round 2: bf16 MFMA GEMMs.
// x (4609, 512); video 8x24x24 = 4608 tokens + 1 BOS. HEADS=8, DHEAD=64.

constexpr int TFR   = 8;
constexpr int SDIM  = 24;
constexpr int NVID  = TFR * SDIM * SDIM;   // 4608
constexpr int NTOK  = NVID + 1;            // 4609
constexpr int NH    = 8;
constexpr int DH    = 64;
constexpr int DM    = 512;
constexpr int NJ    = 28;

typedef __attribute__((ext_vector_type(8))) short bf16x8;
typedef __attribute__((ext_vector_type(4))) float f32x4;

// ---------------------------------------------------------------------------
// fp32 -> bf16 cast (vectorized)
// ---------------------------------------------------------------------------
__global__ __launch_bounds__(256)
void cast_f32_bf16(const float* __restrict__ in, __hip_bfloat16* __restrict__ out, int n)
{
    const int i = (blockIdx.x * 256 + threadIdx.x) * 4;
    if (i >= n) return;
    const float4 v = *(const float4*)(in + i);
    out[i + 0] = __float2bfloat16(v.x);
    out[i + 1] = __float2bfloat16(v.y);
    out[i + 2] = __float2bfloat16(v.z);
    out[i + 3] = __float2bfloat16(v.w);
}

// ---------------------------------------------------------------------------
// W[k][n] fp32 -> Wt[n][k] bf16 (tiled transpose). Kd, Nd multiples of 32.
// ---------------------------------------------------------------------------
__global__ __launch_bounds__(256)
void transpose_cast(const float* __restrict__ W, __hip_bfloat16* __restrict__ Wt,
                    int Kd, int Nd)
{
    __shared__ float t[32][33];
    const int n0 = blockIdx.x * 32, k0 = blockIdx.y * 32;
    const int r  = threadIdx.x >> 3;
    const int c4 = (threadIdx.x & 7) * 4;
    const float4 v = *(const float4*)(W + (size_t)(k0 + r) * Nd + n0 + c4);
    t[r][c4 + 0] = v.x; t[r][c4 + 1] = v.y; t[r][c4 + 2] = v.z; t[r][c4 + 3] = v.w;
    __syncthreads();
    #pragma unroll
    for (int j = 0; j < 4; ++j)
        Wt[(size_t)(n0 + r) * Kd + k0 + c4 + j] = __float2bfloat16(t[c4 + j][r]);
}

// ---------------------------------------------------------------------------
// bf16 MFMA GEMM: C(MxN, f32) = A(MxK, bf16 row-major) @ Bt(NxK, bf16)^T.
// BM=128, BN=64, BK=64. 256 thr = 4 waves in 2x2; wave tile 64x32 (4x2 frags
// of 16x16x32). LDS pitch 72 (9 bank-quads/row: phase-conflict-free b128,
// rows stay 16B-aligned).
// ---------------------------------------------------------------------------
__global__ __launch_bounds__(256)
void gemm_bt_bf16(const __hip_bfloat16* __restrict__ A,
                  const __hip_bfloat16* __restrict__ Bt,
                  float* __restrict__ C, int M, int N, int K,
                  const float* __restrict__ bias)
{
    constexpr int BM = 128, BN = 64, BK = 64, PITCH = 72;
    __shared__ short As[BM * PITCH];
    __shared__ short Bs[BN * PITCH];

    const int tid  = threadIdx.x;
    const int m0   = blockIdx.x * BM;
    const int n0   = blockIdx.y * BN;
    const int lane = tid & 63;
    const int wave = tid >> 6;
    const int wm   = (wave >> 1) * 64;   // wave row offset in tile
    const int wn   = (wave & 1) * 32;    // wave col offset in tile
    const int col  = lane & 15;
    const int quad = lane >> 4;

    f32x4 acc[4][2] = {};

    for (int k0 = 0; k0 < K; k0 += BK) {
        // stage A: 128 rows x 64 k, 8-elem chunks, 4 per thread (coalesced)
        #pragma unroll
        for (int it = 0; it < 4; ++it) {
            const int idx = tid + it * 256;
            const int r = idx >> 3, c = idx & 7;
            const int gr = m0 + r;
            int4 val = make_int4(0, 0, 0, 0);
            if (gr < M)
                val = *(const int4*)(A + (size_t)gr * K + k0 + c * 8);
            *(int4*)(&As[r * PITCH + c * 8]) = val;
        }
        // stage B: 64 rows x 64 k, 2 chunks per thread
        #pragma unroll
        for (int it = 0; it < 2; ++it) {
            const int idx = tid + it * 256;
            const int r = idx >> 3, c = idx & 7;
            const int4 val = *(const int4*)(Bt + (size_t)(n0 + r) * K + k0 + c * 8);
            *(int4*)(&Bs[r * PITCH + c * 8]) = val;
        }
        __syncthreads();

        #pragma unroll
        for (int ks = 0; ks < 2; ++ks) {
            bf16x8 af[4], bfr[2];
            #pragma unroll
            for (int mt = 0; mt < 4; ++mt)
                af[mt] = *(const bf16x8*)(&As[(wm + mt * 16 + col) * PITCH + ks * 32 + quad * 8]);
            #pragma unroll
            for (int nt = 0; nt < 2; ++nt)
                bfr[nt] = *(const bf16x8*)(&Bs[(wn + nt * 16 + col) * PITCH + ks * 32 + quad * 8]);
            #pragma unroll
            for (int mt = 0; mt < 4; ++mt)
                #pragma unroll
                for (int nt = 0; nt < 2; ++nt)
                    acc[mt][nt] = __builtin_amdgcn_mfma_f32_16x16x32_bf16(
                        af[mt], bfr[nt], acc[mt][nt], 0, 0, 0);
        }
        __syncthreads();
    }

    // epilogue: D lane mapping col=lane&15, row=quad*4+reg [m89-verified]
    #pragma unroll
    for (int mt = 0; mt < 4; ++mt) {
        #pragma unroll
        for (int r = 0; r < 4; ++r) {
            const int row = m0 + wm + mt * 16 + quad * 4 + r;
            if (row >= M) continue;
            #pragma unroll
            for (int nt = 0; nt < 2; ++nt) {
                const int cg = n0 + wn + nt * 16 + col;
                float v = acc[mt][nt][r];
                if (bias) v += bias[cg];
                C[(size_t)row * N + cg] = v;
            }
        }
    }
}

// ---------------------------------------------------------------------------
// Fused attention: one block (256 thr) per video query position; fp32 math,
// bf16 output (feeds the bf16 out-projection GEMM).
// KV layout: row r (0..4608) = [K(512) | V(512)], column = h*64+d.
// ---------------------------------------------------------------------------
__global__ __launch_bounds__(256)
void attn_kernel(const float* __restrict__ Q, const float* __restrict__ KV,
                 __hip_bfloat16* __restrict__ O,
                 const float* __restrict__ W_th,
                 const float* __restrict__ ax1, const float* __restrict__ ax2,
                 const float* __restrict__ ax3)
{
    __shared__ float q_s[DM];
    __shared__ float sim_s[NH * NJ];
    __shared__ float mixed_s[NH * NJ];
    __shared__ float bias_s[NH * NJ];
    __shared__ int   row_s[NJ];

    const int tid  = threadIdx.x;
    const int i    = blockIdx.x;
    const int qrow = i + 1;

    q_s[tid]       = Q[(size_t)qrow * DM + tid]       * 0.125f;
    q_s[tid + 256] = Q[(size_t)qrow * DM + tid + 256] * 0.125f;

    if (tid < NJ) {
        int row;
        if (tid == 0) {
            row = 0;
        } else {
            const int jp = tid - 1;
            const int di = jp / 9, dj = (jp / 3) % 3, dk = jp % 3;
            const int t  = i / (SDIM * SDIM);
            const int rm = i % (SDIM * SDIM);
            const int y  = rm / SDIM, x = rm % SDIM;
            const int tt = t + di - 2, yy = y + dj - 2, xx = x + dk - 2;
            row = (tt >= 0 && yy >= 0 && xx >= 0)
                    ? (1 + tt * SDIM * SDIM + yy * SDIM + xx) : -1;
        }
        row_s[tid] = row;
    }
    if (tid < NH * NJ) {
        const int g = tid / NJ, j = tid % NJ;
        float b = 0.f;
        if (j > 0) {
            const int jp = j - 1;
            const int di = jp / 9, dj = (jp / 3) % 3, dk = jp % 3;
            b = ax1[di * NH + g] + ax2[dj * NH + g] + ax3[dk * NH + g];
        }
        bias_s[tid] = b;
    }
    __syncthreads();

    const int wave = tid >> 6;
    const int lane = tid & 63;
    const int sub  = lane >> 4;
    const int ln   = lane & 15;
    #pragma unroll 2
    for (int step = 0; step < 14; ++step) {
        const int p   = step * 16 + wave * 4 + sub;
        const int g   = p / NJ, j = p % NJ;
        const int row = row_s[j];
        float partial = 0.f;
        if (row >= 0) {
            const float4 k4 = *(const float4*)(KV + (size_t)row * 1024 + g * 64 + ln * 4);
            const float4 q4 = *(const float4*)(&q_s[g * 64 + ln * 4]);
            partial = k4.x * q4.x + k4.y * q4.y + k4.z * q4.z + k4.w * q4.w;
        }
        partial += __shfl_xor(partial, 1);
        partial += __shfl_xor(partial, 2);
        partial += __shfl_xor(partial, 4);
        partial += __shfl_xor(partial, 8);
        if (ln == 0)
            sim_s[p] = (row >= 0) ? (partial + bias_s[p]) : -1e30f;
    }
    __syncthreads();

    if (tid < NH) {
        float m = -1e30f;
        #pragma unroll
        for (int j = 0; j < NJ; ++j) m = fmaxf(m, sim_s[tid * NJ + j]);
        float e[NJ], s = 0.f;
        #pragma unroll
        for (int j = 0; j < NJ; ++j) {
            e[j] = __expf(sim_s[tid * NJ + j] - m);
            s += e[j];
        }
        const float inv = 1.f / s;
        #pragma unroll
        for (int j = 0; j < NJ; ++j) sim_s[tid * NJ + j] = e[j] * inv;
    }
    __syncthreads();

    if (tid < NH * NJ) {
        const int h = tid / NJ, j = tid % NJ;
        float acc = 0.f;
        #pragma unroll
        for (int g = 0; g < NH; ++g)
            acc += W_th[h * NH + g] * sim_s[g * NJ + j];
        mixed_s[tid] = acc;
    }
    __syncthreads();

    #pragma unroll
    for (int half = 0; half < 2; ++half) {
        const int c = tid + half * 256;
        const int h = c >> 6;
        float acc = 0.f;
        for (int j = 0; j < NJ; ++j) {
            const int row = row_s[j];
            if (row >= 0)
                acc += mixed_s[h * NJ + j] * KV[(size_t)row * 1024 + 512 + c];
        }
        O[(size_t)qrow * DM + c] = __float2bfloat16(acc);
    }

    if (i == 0) {
        O[tid]       = __float2bfloat16(KV[512 + tid]);
        O[tid + 256] = __float2bfloat16(KV[512 + tid + 256]);
    }
}

// ---------------------------------------------------------------------------
extern "C" void kernel_launch(void* const* d_in, const int* in_sizes, int n_in,
                              void* d_out, int out_size, void* d_ws, size_t ws_size,
                              hipStream_t stream)
{
    const float* x    = (const float*)d_in[0];
    const float* Wq   = (const float*)d_in[1];
    const float* Wkv  = (const float*)d_in[2];
    const float* W_th = (const float*)d_in[3];
    const float* Wout = (const float*)d_in[4];
    const float* bout = (const float*)d_in[5];
    const float* ax1  = (const float*)d_in[6];
    const float* ax2  = (const float*)d_in[7];
    const float* ax3  = (const float*)d_in[8];
    float* out = (float*)d_out;

    // workspace layout
    char* p = (char*)d_ws;
    float* Q  = (float*)p;              p += (size_t)NTOK * DM * 4;
    float* KV = (float*)p;              p += (size_t)NTOK * 2 * DM * 4;
    __hip_bfloat16* Xb    = (__hip_bfloat16*)p; p += (size_t)NTOK * DM * 2;
    __hip_bfloat16* Ob    = (__hip_bfloat16*)p; p += (size_t)NTOK * DM * 2;
    __hip_bfloat16* Wqt   = (__hip_bfloat16*)p; p += (size_t)DM * DM * 2;
    __hip_bfloat16* Wkvt  = (__hip_bfloat16*)p; p += (size_t)DM * 2 * DM * 2;
    __hip_bfloat16* Woutt = (__hip_bfloat16*)p; p += (size_t)DM * DM * 2;

    const dim3 blk(256);
    const int mtiles = (NTOK + 127) / 128;   // 37

    cast_f32_bf16<<<(NTOK * DM / 4 + 255) / 256, blk, 0, stream>>>(x, Xb, NTOK * DM);
    transpose_cast<<<dim3(DM / 32, DM / 32),     blk, 0, stream>>>(Wq,   Wqt,   DM, DM);
    transpose_cast<<<dim3(2 * DM / 32, DM / 32), blk, 0, stream>>>(Wkv,  Wkvt,  DM, 2 * DM);
    transpose_cast<<<dim3(DM / 32, DM / 32),     blk, 0, stream>>>(Wout, Woutt, DM, DM);

    gemm_bt_bf16<<<dim3(mtiles, DM / 64),     blk, 0, stream>>>(Xb, Wqt,  Q,  NTOK, DM,     DM, nullptr);
    gemm_bt_bf16<<<dim3(mtiles, 2 * DM / 64), blk, 0, stream>>>(Xb, Wkvt, KV, NTOK, 2 * DM, DM, nullptr);

    attn_kernel<<<dim3(NVID), blk, 0, stream>>>(Q, KV, Ob, W_th, ax1, ax2, ax3);

    gemm_bt_bf16<<<dim3(mtiles, DM / 64),     blk, 0, stream>>>(Ob, Woutt, out, NTOK, DM, DM, bout);
}

// Round 3
// 141.645 us; speedup vs baseline: 2.1276x; 1.5591x over previous
//
#include <hip/hip_runtime.h>
#include <hip/hip_bf16.h>

// Sparse 3D neighborhood attention (causal), MI355X. Round 3:
// wave-per-query attention + bf16 KV gather + fused QKV GEMM + merged prep.

constexpr int TFR   = 8;
constexpr int SDIM  = 24;
constexpr int NVID  = TFR * SDIM * SDIM;   // 4608
constexpr int NTOK  = NVID + 1;            // 4609
constexpr int NH    = 8;
constexpr int DM    = 512;
constexpr int NJ    = 28;

typedef __attribute__((ext_vector_type(8))) short bf16x8;
typedef __attribute__((ext_vector_type(8))) unsigned short ushort8;
typedef __attribute__((ext_vector_type(4))) float f32x4;

__device__ __forceinline__ float bf2f(unsigned short u) {
    return __uint_as_float((unsigned)u << 16);
}
__device__ __forceinline__ unsigned short f2bf(float f) {
    __hip_bfloat16 h = __float2bfloat16(f);
    return reinterpret_cast<unsigned short&>(h);
}

// ---------------------------------------------------------------------------
// Merged prep: cast x -> bf16, and transpose+cast Wq/Wkv (into one 1536x512
// buffer) and Wout. One launch.
// ---------------------------------------------------------------------------
constexpr int CAST_BLOCKS = (NTOK * DM / 4 + 255) / 256;   // 2305

__global__ __launch_bounds__(256)
void prep_kernel(const float* __restrict__ x,
                 const float* __restrict__ Wq, const float* __restrict__ Wkv,
                 const float* __restrict__ Wout,
                 __hip_bfloat16* __restrict__ Xb,
                 __hip_bfloat16* __restrict__ Wqkvt,
                 __hip_bfloat16* __restrict__ Woutt)
{
    const int b   = blockIdx.x;
    const int tid = threadIdx.x;

    if (b < CAST_BLOCKS) {
        const int i = (b * 256 + tid) * 4;
        if (i >= NTOK * DM) return;
        const float4 v = *(const float4*)(x + i);
        Xb[i + 0] = __float2bfloat16(v.x);
        Xb[i + 1] = __float2bfloat16(v.y);
        Xb[i + 2] = __float2bfloat16(v.z);
        Xb[i + 3] = __float2bfloat16(v.w);
        return;
    }

    __shared__ float t[32][33];
    int tb = b - CAST_BLOCKS;
    const float* W; __hip_bfloat16* Wt; int Nd, tX, rowOff;
    if (tb < 256)      { W = Wq;   Wt = Wqkvt; Nd = 512;  tX = 16; rowOff = 0;   }
    else if (tb < 768) { tb -= 256; W = Wkv;  Wt = Wqkvt; Nd = 1024; tX = 32; rowOff = 512; }
    else               { tb -= 768; W = Wout; Wt = Woutt; Nd = 512;  tX = 16; rowOff = 0;   }
    const int n0 = (tb % tX) * 32, k0 = (tb / tX) * 32;
    const int r  = tid >> 3;
    const int c4 = (tid & 7) * 4;
    const float4 v = *(const float4*)(W + (size_t)(k0 + r) * Nd + n0 + c4);
    t[r][c4 + 0] = v.x; t[r][c4 + 1] = v.y; t[r][c4 + 2] = v.z; t[r][c4 + 3] = v.w;
    __syncthreads();
    #pragma unroll
    for (int j = 0; j < 4; ++j)
        Wt[(size_t)(rowOff + n0 + r) * 512 + k0 + c4 + j] = __float2bfloat16(t[c4 + j][r]);
}

// ---------------------------------------------------------------------------
// bf16 MFMA GEMM, BM=BN=64, BK=64, 256 thr = 4 waves (2x2), wave tile 32x32.
// MODE 0: C fp32 (+bias). MODE 1: qkv split — col<512 -> fp32 Q, else bf16 KV.
// ---------------------------------------------------------------------------
template<int MODE>
__global__ __launch_bounds__(256)
void gemm_bt(const __hip_bfloat16* __restrict__ A,
             const __hip_bfloat16* __restrict__ Bt,
             float* __restrict__ C, __hip_bfloat16* __restrict__ Cb,
             int M, int N, int K, const float* __restrict__ bias)
{
    constexpr int BM = 64, BN = 64, BK = 64, PITCH = 72;
    __shared__ short As[BM * PITCH];
    __shared__ short Bs[BN * PITCH];

    const int tid  = threadIdx.x;
    const int m0   = blockIdx.x * BM;
    const int n0   = blockIdx.y * BN;
    const int lane = tid & 63;
    const int wave = tid >> 6;
    const int wm   = (wave >> 1) * 32;
    const int wn   = (wave & 1) * 32;
    const int col  = lane & 15;
    const int quad = lane >> 4;

    f32x4 acc[2][2] = {};

    for (int k0 = 0; k0 < K; k0 += BK) {
        #pragma unroll
        for (int it = 0; it < 2; ++it) {
            const int idx = tid + it * 256;
            const int r = idx >> 3, c = idx & 7;
            const int gr = m0 + r;
            int4 val = make_int4(0, 0, 0, 0);
            if (gr < M)
                val = *(const int4*)(A + (size_t)gr * K + k0 + c * 8);
            *(int4*)(&As[r * PITCH + c * 8]) = val;
        }
        #pragma unroll
        for (int it = 0; it < 2; ++it) {
            const int idx = tid + it * 256;
            const int r = idx >> 3, c = idx & 7;
            const int4 val = *(const int4*)(Bt + (size_t)(n0 + r) * K + k0 + c * 8);
            *(int4*)(&Bs[r * PITCH + c * 8]) = val;
        }
        __syncthreads();

        #pragma unroll
        for (int ks = 0; ks < 2; ++ks) {
            bf16x8 af[2], bfr[2];
            #pragma unroll
            for (int mt = 0; mt < 2; ++mt)
                af[mt] = *(const bf16x8*)(&As[(wm + mt * 16 + col) * PITCH + ks * 32 + quad * 8]);
            #pragma unroll
            for (int nt = 0; nt < 2; ++nt)
                bfr[nt] = *(const bf16x8*)(&Bs[(wn + nt * 16 + col) * PITCH + ks * 32 + quad * 8]);
            #pragma unroll
            for (int mt = 0; mt < 2; ++mt)
                #pragma unroll
                for (int nt = 0; nt < 2; ++nt)
                    acc[mt][nt] = __builtin_amdgcn_mfma_f32_16x16x32_bf16(
                        af[mt], bfr[nt], acc[mt][nt], 0, 0, 0);
        }
        __syncthreads();
    }

    #pragma unroll
    for (int mt = 0; mt < 2; ++mt) {
        #pragma unroll
        for (int r = 0; r < 4; ++r) {
            const int row = m0 + wm + mt * 16 + quad * 4 + r;
            if (row >= M) continue;
            #pragma unroll
            for (int nt = 0; nt < 2; ++nt) {
                const int cg = n0 + wn + nt * 16 + col;
                float v = acc[mt][nt][r];
                if (MODE == 0) {
                    if (bias) v += bias[cg];
                    C[(size_t)row * N + cg] = v;
                } else {
                    if (cg < 512) C[(size_t)row * 512 + cg] = v;
                    else          Cb[(size_t)row * 1024 + (cg - 512)] = __float2bfloat16(v);
                }
            }
        }
    }
}

// ---------------------------------------------------------------------------
// Attention v2: one wave per query; 4 queries per 256-thr block.
// Lane l = g*8+s owns columns [l*8, l*8+8) (head g = l>>3).
// KVb: bf16, row r = [K(512) | V(512)]. Q fp32. Output bf16.
// ---------------------------------------------------------------------------
__global__ __launch_bounds__(256)
void attn_v2(const float* __restrict__ Q, const __hip_bfloat16* __restrict__ KVb,
             __hip_bfloat16* __restrict__ O,
             const float* __restrict__ W_th,
             const float* __restrict__ ax1, const float* __restrict__ ax2,
             const float* __restrict__ ax3)
{
    __shared__ float attn_s[4][NH * NJ];
    __shared__ float mixed_s[4][NH * NJ];

    const int tid  = threadIdx.x;
    const int wave = tid >> 6;
    const int lane = tid & 63;
    const int g    = lane >> 3;
    const int s    = lane & 7;
    const int i    = __builtin_amdgcn_readfirstlane(blockIdx.x * 4 + (tid >> 6));
    const int qrow = i + 1;

    const int t  = i / (SDIM * SDIM);
    const int rm = i % (SDIM * SDIM);
    const int y  = rm / SDIM;
    const int x  = rm % SDIM;

    // q fragment (scaled), 8 floats per lane
    float qf[8];
    {
        const float4 q0 = *(const float4*)(Q + (size_t)qrow * DM + lane * 8);
        const float4 q1 = *(const float4*)(Q + (size_t)qrow * DM + lane * 8 + 4);
        qf[0] = q0.x * 0.125f; qf[1] = q0.y * 0.125f; qf[2] = q0.z * 0.125f; qf[3] = q0.w * 0.125f;
        qf[4] = q1.x * 0.125f; qf[5] = q1.y * 0.125f; qf[6] = q1.z * 0.125f; qf[7] = q1.w * 0.125f;
    }
    // per-lane bias components for head g
    float a1[3], a2[3], a3[3];
    #pragma unroll
    for (int d = 0; d < 3; ++d) {
        a1[d] = ax1[d * NH + g];
        a2[d] = ax2[d * NH + g];
        a3[d] = ax3[d * NH + g];
    }

    // ---- sim pass: unrolled over 28 neighbors --------------------------------
    float sim[NJ];
    #pragma unroll
    for (int j = 0; j < NJ; ++j) {
        int row; bool valid; float bias;
        if (j == 0) { row = 0; valid = true; bias = 0.f; }
        else {
            const int jp = j - 1;
            const int di = jp / 9, dj = (jp / 3) % 3, dk = jp % 3;
            const int tt = t + di - 2, yy = y + dj - 2, xx = x + dk - 2;
            valid = (tt >= 0) && (yy >= 0) && (xx >= 0);
            row = 1 + tt * SDIM * SDIM + yy * SDIM + xx;
            bias = a1[di] + a2[dj] + a3[dk];
        }
        if (valid) {
            const ushort8 kv = *(const ushort8*)(KVb + (size_t)row * 1024 + lane * 8);
            float p = 0.f;
            #pragma unroll
            for (int e = 0; e < 8; ++e) p += bf2f(kv[e]) * qf[e];
            p += __shfl_xor(p, 1);
            p += __shfl_xor(p, 2);
            p += __shfl_xor(p, 4);
            sim[j] = p + bias;
        } else {
            sim[j] = -1e30f;
        }
    }

    // ---- softmax (redundant in all lanes of the 8-lane group — lockstep) ----
    float m = -1e30f;
    #pragma unroll
    for (int j = 0; j < NJ; ++j) m = fmaxf(m, sim[j]);
    float ssum = 0.f;
    #pragma unroll
    for (int j = 0; j < NJ; ++j) { sim[j] = __expf(sim[j] - m); ssum += sim[j]; }
    const float inv = 1.f / ssum;
    #pragma unroll
    for (int j = 0; j < NJ; ++j) sim[j] *= inv;

    // lane s==0 of each head group writes attn row (28 floats, 7x float4)
    if (s == 0) {
        #pragma unroll
        for (int u = 0; u < 7; ++u) {
            f32x4 v4 = { sim[4*u], sim[4*u+1], sim[4*u+2], sim[4*u+3] };
            *(f32x4*)(&attn_s[wave][g * NJ + 4 * u]) = v4;
        }
    }
    __syncthreads();

    // ---- talking-heads mix (cooperative across the block) -------------------
    if (tid < NH * NJ) {
        const int h = tid / NJ, j = tid % NJ;
        #pragma unroll
        for (int q = 0; q < 4; ++q) {
            float acc = 0.f;
            #pragma unroll
            for (int gg = 0; gg < NH; ++gg)
                acc += W_th[h * NH + gg] * attn_s[q][gg * NJ + j];
            mixed_s[q][h * NJ + j] = acc;
        }
    }
    __syncthreads();

    // ---- V pass -------------------------------------------------------------
    float acc8[8] = {};
    #pragma unroll
    for (int j = 0; j < NJ; ++j) {
        int row; bool valid;
        if (j == 0) { row = 0; valid = true; }
        else {
            const int jp = j - 1;
            const int di = jp / 9, dj = (jp / 3) % 3, dk = jp % 3;
            const int tt = t + di - 2, yy = y + dj - 2, xx = x + dk - 2;
            valid = (tt >= 0) && (yy >= 0) && (xx >= 0);
            row = 1 + tt * SDIM * SDIM + yy * SDIM + xx;
        }
        if (valid) {
            const ushort8 vv = *(const ushort8*)(KVb + (size_t)row * 1024 + 512 + lane * 8);
            const float w = mixed_s[wave][g * NJ + j];
            #pragma unroll
            for (int e = 0; e < 8; ++e) acc8[e] += w * bf2f(vv[e]);
        }
    }

    ushort8 o;
    #pragma unroll
    for (int e = 0; e < 8; ++e) o[e] = f2bf(acc8[e]);
    *(ushort8*)(O + (size_t)qrow * DM + lane * 8) = o;

    // BOS output row = V row 0 (already bf16 — straight copy)
    if (i == 0) {
        const ushort8 vb = *(const ushort8*)(KVb + 512 + lane * 8);
        *(ushort8*)(O + lane * 8) = vb;
    }
}

// ---------------------------------------------------------------------------
extern "C" void kernel_launch(void* const* d_in, const int* in_sizes, int n_in,
                              void* d_out, int out_size, void* d_ws, size_t ws_size,
                              hipStream_t stream)
{
    const float* x    = (const float*)d_in[0];
    const float* Wq   = (const float*)d_in[1];
    const float* Wkv  = (const float*)d_in[2];
    const float* W_th = (const float*)d_in[3];
    const float* Wout = (const float*)d_in[4];
    const float* bout = (const float*)d_in[5];
    const float* ax1  = (const float*)d_in[6];
    const float* ax2  = (const float*)d_in[7];
    const float* ax3  = (const float*)d_in[8];
    float* out = (float*)d_out;

    char* p = (char*)d_ws;
    float* Qf = (float*)p;                         p += (size_t)NTOK * DM * 4;
    __hip_bfloat16* KVb   = (__hip_bfloat16*)p;    p += (size_t)NTOK * 2 * DM * 2;
    __hip_bfloat16* Xb    = (__hip_bfloat16*)p;    p += (size_t)NTOK * DM * 2;
    __hip_bfloat16* Ob    = (__hip_bfloat16*)p;    p += (size_t)NTOK * DM * 2;
    __hip_bfloat16* Wqkvt = (__hip_bfloat16*)p;    p += (size_t)3 * DM * DM * 2;
    __hip_bfloat16* Woutt = (__hip_bfloat16*)p;    p += (size_t)DM * DM * 2;

    const dim3 blk(256);
    const int mtiles = (NTOK + 63) / 64;   // 73

    prep_kernel<<<CAST_BLOCKS + 1024, blk, 0, stream>>>(x, Wq, Wkv, Wout, Xb, Wqkvt, Woutt);

    gemm_bt<1><<<dim3(mtiles, 24), blk, 0, stream>>>(Xb, Wqkvt, Qf, KVb,
                                                     NTOK, 3 * DM, DM, nullptr);

    attn_v2<<<dim3(NVID / 4), blk, 0, stream>>>(Qf, KVb, Ob, W_th, ax1, ax2, ax3);

    gemm_bt<0><<<dim3(mtiles, 8), blk, 0, stream>>>(Ob, Woutt, out, nullptr,
                                                    NTOK, DM, DM, bout);
}

// Round 4
// 140.203 us; speedup vs baseline: 2.1495x; 1.0103x over previous
//
#include <hip/hip_runtime.h>
#include <hip/hip_bf16.h>

// Sparse 3D neighborhood attention (causal), MI355X. Round 4:
// m97-style MFMA GEMM (global_load_lds + XOR-swizzled LDS, 64x64 wave tile).

constexpr int TFR   = 8;
constexpr int SDIM  = 24;
constexpr int NVID  = TFR * SDIM * SDIM;   // 4608
constexpr int NTOK  = NVID + 1;            // 4609
constexpr int NH    = 8;
constexpr int DM    = 512;
constexpr int NJ    = 28;

typedef __attribute__((ext_vector_type(8))) short bf16x8;
typedef __attribute__((ext_vector_type(8))) unsigned short ushort8;
typedef __attribute__((ext_vector_type(4))) float f32x4;

typedef const __attribute__((address_space(1))) unsigned int* gas_ptr;
typedef __attribute__((address_space(3))) unsigned int* las_ptr;

__device__ __forceinline__ float bf2f(unsigned short u) {
    return __uint_as_float((unsigned)u << 16);
}

// ---------------------------------------------------------------------------
// Merged prep: cast x -> bf16; transpose+cast Wq/Wkv (one 1536x512 buffer) and
// Wout. One launch.
// ---------------------------------------------------------------------------
constexpr int CAST_BLOCKS = (NTOK * DM / 4 + 255) / 256;   // 2305

__global__ __launch_bounds__(256)
void prep_kernel(const float* __restrict__ x,
                 const float* __restrict__ Wq, const float* __restrict__ Wkv,
                 const float* __restrict__ Wout,
                 __hip_bfloat16* __restrict__ Xb,
                 __hip_bfloat16* __restrict__ Wqkvt,
                 __hip_bfloat16* __restrict__ Woutt)
{
    const int b   = blockIdx.x;
    const int tid = threadIdx.x;

    if (b < CAST_BLOCKS) {
        const int i = (b * 256 + tid) * 4;
        if (i >= NTOK * DM) return;
        const float4 v = *(const float4*)(x + i);
        Xb[i + 0] = __float2bfloat16(v.x);
        Xb[i + 1] = __float2bfloat16(v.y);
        Xb[i + 2] = __float2bfloat16(v.z);
        Xb[i + 3] = __float2bfloat16(v.w);
        return;
    }

    __shared__ float t[32][33];
    int tb = b - CAST_BLOCKS;
    const float* W; __hip_bfloat16* Wt; int Nd, tX, rowOff;
    if (tb < 256)      { W = Wq;   Wt = Wqkvt; Nd = 512;  tX = 16; rowOff = 0;   }
    else if (tb < 768) { tb -= 256; W = Wkv;  Wt = Wqkvt; Nd = 1024; tX = 32; rowOff = 512; }
    else               { tb -= 768; W = Wout; Wt = Woutt; Nd = 512;  tX = 16; rowOff = 0;   }
    const int n0 = (tb % tX) * 32, k0 = (tb / tX) * 32;
    const int r  = tid >> 3;
    const int c4 = (tid & 7) * 4;
    const float4 v = *(const float4*)(W + (size_t)(k0 + r) * Nd + n0 + c4);
    t[r][c4 + 0] = v.x; t[r][c4 + 1] = v.y; t[r][c4 + 2] = v.z; t[r][c4 + 3] = v.w;
    __syncthreads();
    #pragma unroll
    for (int j = 0; j < 4; ++j)
        Wt[(size_t)(rowOff + n0 + r) * 512 + k0 + c4 + j] = __float2bfloat16(t[c4 + j][r]);
}

// ---------------------------------------------------------------------------
// m97-style bf16 MFMA GEMM: C = A(MxK) @ Bt(NxK)^T. BK=64, 4 waves (2x2),
// wave tile (AM*16)x(AN*16). Staging: global_load_lds width 16, LDS linear in
// DMA order; XOR swizzle (unit ^ row&7) applied to the GLOBAL source address
// so frag ds_read_b128 spreads over all 8 bank groups (2-way = free).
// MODE 0: fp32 C (+bias). MODE 1: qkv split — n0<512 -> fp32 Q, else bf16 KV.
// A-tail OOB rows DMA garbage; only C rows >= M are affected (never stored).
// ---------------------------------------------------------------------------
template<int BM, int BN, int AM, int AN, int MODE>
__global__ __launch_bounds__(256)
void gemm_mfma(const __hip_bfloat16* __restrict__ A,
               const __hip_bfloat16* __restrict__ Bt,
               float* __restrict__ C, __hip_bfloat16* __restrict__ Cb,
               int M, int N, int K, const float* __restrict__ bias)
{
    constexpr int BK = 64;                 // k-elements (shorts) per tile row
    __shared__ __align__(16) short As[BM * BK];
    __shared__ __align__(16) short Bs[BN * BK];

    const int tid  = threadIdx.x;
    const int m0   = blockIdx.x * BM;
    const int n0   = blockIdx.y * BN;
    const int lane = tid & 63;
    const int wave = tid >> 6;
    const int wm   = (wave >> 1) * (AM * 16);
    const int wn   = (wave & 1) * (AN * 16);
    const int col  = lane & 15;
    const int quad = lane >> 4;

    f32x4 acc[AM][AN] = {};

    for (int k0 = 0; k0 < K; k0 += BK) {
        // ---- stage A: BM rows x 8 units(16B) via global_load_lds ----------
        #pragma unroll
        for (int it = 0; it < BM * 8 / 256; ++it) {
            const int idx = it * 256 + tid;            // chunk id == LDS slot
            const int r   = idx >> 3;
            const int u   = (idx & 7) ^ (r & 7);       // swizzled source unit
            const __hip_bfloat16* gp = A + (size_t)(m0 + r) * K + k0 + u * 8;
            __builtin_amdgcn_global_load_lds(
                (gas_ptr)gp, (las_ptr)&As[(it * 256 + wave * 64) * 8], 16, 0, 0);
        }
        // ---- stage B ------------------------------------------------------
        #pragma unroll
        for (int it = 0; it < BN * 8 / 256; ++it) {
            const int idx = it * 256 + tid;
            const int r   = idx >> 3;
            const int u   = (idx & 7) ^ (r & 7);
            const __hip_bfloat16* gp = Bt + (size_t)(n0 + r) * K + k0 + u * 8;
            __builtin_amdgcn_global_load_lds(
                (gas_ptr)gp, (las_ptr)&Bs[(it * 256 + wave * 64) * 8], 16, 0, 0);
        }
        __syncthreads();

        #pragma unroll
        for (int ks = 0; ks < 2; ++ks) {
            bf16x8 af[AM], bfr[AN];
            #pragma unroll
            for (int mt = 0; mt < AM; ++mt) {
                const int r = wm + mt * 16 + col;
                const int u = (ks * 4 + quad) ^ (r & 7);
                af[mt] = *(const bf16x8*)(&As[r * BK + u * 8]);
            }
            #pragma unroll
            for (int nt = 0; nt < AN; ++nt) {
                const int r = wn + nt * 16 + col;
                const int u = (ks * 4 + quad) ^ (r & 7);
                bfr[nt] = *(const bf16x8*)(&Bs[r * BK + u * 8]);
            }
            #pragma unroll
            for (int mt = 0; mt < AM; ++mt)
                #pragma unroll
                for (int nt = 0; nt < AN; ++nt)
                    acc[mt][nt] = __builtin_amdgcn_mfma_f32_16x16x32_bf16(
                        af[mt], bfr[nt], acc[mt][nt], 0, 0, 0);
        }
        __syncthreads();
    }

    // epilogue: D mapping col=lane&15, row=quad*4+reg [m89-verified]
    const bool isQ = (MODE == 1) && (n0 < 512);
    #pragma unroll
    for (int mt = 0; mt < AM; ++mt) {
        #pragma unroll
        for (int r = 0; r < 4; ++r) {
            const int row = m0 + wm + mt * 16 + quad * 4 + r;
            if (row >= M) continue;
            #pragma unroll
            for (int nt = 0; nt < AN; ++nt) {
                const int cg = n0 + wn + nt * 16 + col;
                float v = acc[mt][nt][r];
                if (MODE == 0) {
                    if (bias) v += bias[cg];
                    C[(size_t)row * N + cg] = v;
                } else if (isQ) {
                    C[(size_t)row * 512 + cg] = v;
                } else {
                    Cb[(size_t)row * 1024 + (cg - 512)] = __float2bfloat16(v);
                }
            }
        }
    }
}

// ---------------------------------------------------------------------------
// Attention: one wave per query; 4 queries per block. Lane l = g*8+s owns
// columns [l*8, l*8+8). KVb bf16: row = [K(512) | V(512)]. Q fp32, O bf16.
// ---------------------------------------------------------------------------
__global__ __launch_bounds__(256)
void attn_v2(const float* __restrict__ Q, const __hip_bfloat16* __restrict__ KVb,
             __hip_bfloat16* __restrict__ O,
             const float* __restrict__ W_th,
             const float* __restrict__ ax1, const float* __restrict__ ax2,
             const float* __restrict__ ax3)
{
    __shared__ float attn_s[4][NH * NJ];
    __shared__ float mixed_s[4][NH * NJ];

    const int tid  = threadIdx.x;
    const int wave = tid >> 6;
    const int lane = tid & 63;
    const int g    = lane >> 3;
    const int s    = lane & 7;
    const int i    = __builtin_amdgcn_readfirstlane(blockIdx.x * 4 + (tid >> 6));
    const int qrow = i + 1;

    const int t  = i / (SDIM * SDIM);
    const int rm = i % (SDIM * SDIM);
    const int y  = rm / SDIM;
    const int x  = rm % SDIM;

    float qf[8];
    {
        const float4 q0 = *(const float4*)(Q + (size_t)qrow * DM + lane * 8);
        const float4 q1 = *(const float4*)(Q + (size_t)qrow * DM + lane * 8 + 4);
        qf[0] = q0.x * 0.125f; qf[1] = q0.y * 0.125f; qf[2] = q0.z * 0.125f; qf[3] = q0.w * 0.125f;
        qf[4] = q1.x * 0.125f; qf[5] = q1.y * 0.125f; qf[6] = q1.z * 0.125f; qf[7] = q1.w * 0.125f;
    }
    float a1[3], a2[3], a3[3];
    #pragma unroll
    for (int d = 0; d < 3; ++d) {
        a1[d] = ax1[d * NH + g];
        a2[d] = ax2[d * NH + g];
        a3[d] = ax3[d * NH + g];
    }

    float sim[NJ];
    #pragma unroll
    for (int j = 0; j < NJ; ++j) {
        int row; bool valid; float bias;
        if (j == 0) { row = 0; valid = true; bias = 0.f; }
        else {
            const int jp = j - 1;
            const int di = jp / 9, dj = (jp / 3) % 3, dk = jp % 3;
            const int tt = t + di - 2, yy = y + dj - 2, xx = x + dk - 2;
            valid = (tt >= 0) && (yy >= 0) && (xx >= 0);
            row = 1 + tt * SDIM * SDIM + yy * SDIM + xx;
            bias = a1[di] + a2[dj] + a3[dk];
        }
        if (valid) {
            const ushort8 kv = *(const ushort8*)(KVb + (size_t)row * 1024 + lane * 8);
            float p = 0.f;
            #pragma unroll
            for (int e = 0; e < 8; ++e) p += bf2f(kv[e]) * qf[e];
            p += __shfl_xor(p, 1);
            p += __shfl_xor(p, 2);
            p += __shfl_xor(p, 4);
            sim[j] = p + bias;
        } else {
            sim[j] = -1e30f;
        }
    }

    float m = -1e30f;
    #pragma unroll
    for (int j = 0; j < NJ; ++j) m = fmaxf(m, sim[j]);
    float ssum = 0.f;
    #pragma unroll
    for (int j = 0; j < NJ; ++j) { sim[j] = __expf(sim[j] - m); ssum += sim[j]; }
    const float inv = 1.f / ssum;
    #pragma unroll
    for (int j = 0; j < NJ; ++j) sim[j] *= inv;

    if (s == 0) {
        #pragma unroll
        for (int u = 0; u < 7; ++u) {
            f32x4 v4 = { sim[4*u], sim[4*u+1], sim[4*u+2], sim[4*u+3] };
            *(f32x4*)(&attn_s[wave][g * NJ + 4 * u]) = v4;
        }
    }
    __syncthreads();

    if (tid < NH * NJ) {
        const int h = tid / NJ, j = tid % NJ;
        #pragma unroll
        for (int q = 0; q < 4; ++q) {
            float acc = 0.f;
            #pragma unroll
            for (int gg = 0; gg < NH; ++gg)
                acc += W_th[h * NH + gg] * attn_s[q][gg * NJ + j];
            mixed_s[q][h * NJ + j] = acc;
        }
    }
    __syncthreads();

    float acc8[8] = {};
    #pragma unroll
    for (int j = 0; j < NJ; ++j) {
        int row; bool valid;
        if (j == 0) { row = 0; valid = true; }
        else {
            const int jp = j - 1;
            const int di = jp / 9, dj = (jp / 3) % 3, dk = jp % 3;
            const int tt = t + di - 2, yy = y + dj - 2, xx = x + dk - 2;
            valid = (tt >= 0) && (yy >= 0) && (xx >= 0);
            row = 1 + tt * SDIM * SDIM + yy * SDIM + xx;
        }
        if (valid) {
            const ushort8 vv = *(const ushort8*)(KVb + (size_t)row * 1024 + 512 + lane * 8);
            const float w = mixed_s[wave][g * NJ + j];
            #pragma unroll
            for (int e = 0; e < 8; ++e) acc8[e] += w * bf2f(vv[e]);
        }
    }

    __hip_bfloat16 o[8];
    #pragma unroll
    for (int e = 0; e < 8; ++e) o[e] = __float2bfloat16(acc8[e]);
    *(ushort8*)(O + (size_t)qrow * DM + lane * 8) = *(const ushort8*)o;

    if (i == 0) {
        const ushort8 vb = *(const ushort8*)(KVb + 512 + lane * 8);
        *(ushort8*)(O + lane * 8) = vb;
    }
}

// ---------------------------------------------------------------------------
extern "C" void kernel_launch(void* const* d_in, const int* in_sizes, int n_in,
                              void* d_out, int out_size, void* d_ws, size_t ws_size,
                              hipStream_t stream)
{
    const float* x    = (const float*)d_in[0];
    const float* Wq   = (const float*)d_in[1];
    const float* Wkv  = (const float*)d_in[2];
    const float* W_th = (const float*)d_in[3];
    const float* Wout = (const float*)d_in[4];
    const float* bout = (const float*)d_in[5];
    const float* ax1  = (const float*)d_in[6];
    const float* ax2  = (const float*)d_in[7];
    const float* ax3  = (const float*)d_in[8];
    float* out = (float*)d_out;

    char* p = (char*)d_ws;
    float* Qf = (float*)p;                         p += (size_t)NTOK * DM * 4;
    __hip_bfloat16* KVb   = (__hip_bfloat16*)p;    p += (size_t)NTOK * 2 * DM * 2;
    __hip_bfloat16* Xb    = (__hip_bfloat16*)p;    p += (size_t)NTOK * DM * 2;
    __hip_bfloat16* Ob    = (__hip_bfloat16*)p;    p += (size_t)NTOK * DM * 2;
    __hip_bfloat16* Wqkvt = (__hip_bfloat16*)p;    p += (size_t)3 * DM * DM * 2;
    __hip_bfloat16* Woutt = (__hip_bfloat16*)p;    p += (size_t)DM * DM * 2;

    const dim3 blk(256);
    const int mtiles = (NTOK + 127) / 128;   // 37

    prep_kernel<<<CAST_BLOCKS + 1024, blk, 0, stream>>>(x, Wq, Wkv, Wout, Xb, Wqkvt, Woutt);

    // QKV: 4609 x 1536 x 512, dual epilogue (Q fp32 | KV bf16)
    gemm_mfma<128, 128, 4, 4, 1><<<dim3(mtiles, 12), blk, 0, stream>>>(
        Xb, Wqkvt, Qf, KVb, NTOK, 3 * DM, DM, nullptr);

    attn_v2<<<dim3(NVID / 4), blk, 0, stream>>>(Qf, KVb, Ob, W_th, ax1, ax2, ax3);

    // out-proj: 4609 x 512 x 512 (+bias)
    gemm_mfma<128, 64, 4, 2, 0><<<dim3(mtiles, 8), blk, 0, stream>>>(
        Ob, Woutt, out, nullptr, NTOK, DM, DM, bout);
}